// Round 3
// baseline (421.724 us; speedup 1.0000x reference)
//
#include <hip/hip_runtime.h>
#include <hip/hip_bf16.h>

#define NROWS 16384
#define MCOLS 4096
#define DDIM  128
#define LOG2E 1.4426950408889634f

typedef __attribute__((ext_vector_type(8))) short short8;
typedef __attribute__((ext_vector_type(4))) float f32x4;
typedef unsigned long long u64;

__device__ __forceinline__ float wave_reduce_add(float d) {
#pragma unroll
  for (int off = 32; off >= 1; off >>= 1) d += __shfl_xor(d, off, 64);
  return d;
}

__device__ __forceinline__ float pcalc(float t, int m) {
  float u = fmaxf(t, 0.2f * t);   // leaky_relu (commutes with positive log2e scaling)
  float e = exp2f(u);             // inputs pre-scaled by log2e
  return m != 0 ? e : 0.f;
}

// round-to-nearest-even f32 -> bf16 (valid for finite non-NaN inputs)
__device__ __forceinline__ unsigned short f2bf(float f) {
  unsigned u = __builtin_bit_cast(unsigned, f);
  return (unsigned short)((u + 0x7fffu + ((u >> 16) & 1u)) >> 16);
}

__device__ __forceinline__ unsigned pack_bf2(float lo, float hi) {
  return (unsigned)f2bf(lo) | ((unsigned)f2bf(hi) << 16);
}

// ---------------------------------------------------------------------------
// K0: bit-pack neigh_matrix (268 MB int32) -> bitmask (8.4 MB, bit j of byte b
// of row r == nm[r][b*8+j]). Pure streaming kernel: this carries the one
// unavoidable HBM stream at full BW with zero latency-sensitivity.
// Block = 16384 ints (4 rows). 8 rounds x (2 consecutive int4 per thread).
// ---------------------------------------------------------------------------
__global__ __launch_bounds__(256) void aggr_pack(
    const int4* __restrict__ nm4, u64* __restrict__ bm64) {
  __shared__ unsigned char sB[2048];
  const int t = threadIdx.x;
  const long blk = blockIdx.x;  // 4096 blocks
#pragma unroll
  for (int j = 0; j < 8; ++j) {
    int4 a = nm4[blk * 4096 + j * 512 + t * 2];
    int4 b = nm4[blk * 4096 + j * 512 + t * 2 + 1];
    unsigned byte =
        (a.x != 0 ? 1u : 0u) | (a.y != 0 ? 2u : 0u) | (a.z != 0 ? 4u : 0u) |
        (a.w != 0 ? 8u : 0u) | (b.x != 0 ? 16u : 0u) | (b.y != 0 ? 32u : 0u) |
        (b.z != 0 ? 64u : 0u) | (b.w != 0 ? 128u : 0u);
    sB[j * 256 + t] = (unsigned char)byte;
  }
  __syncthreads();
  u64 w = *(const u64*)&sB[t * 8];
  bm64[blk * 256 + t] = w;
}

// ---------------------------------------------------------------------------
// K1: s_neigh' = (V @ a_neigh)*log2e ; pack V -> bf16 in MFMA-B fragment order.
// ---------------------------------------------------------------------------
__global__ __launch_bounds__(256) void aggr_prep(
    const float* __restrict__ V, const float* __restrict__ a,
    float* __restrict__ sneigh, short* __restrict__ packedV) {
  const int t = threadIdx.x, lane = t & 63, w = t >> 6;
  const int blk = blockIdx.x;  // 0..255

  float a0 = a[DDIM + 2 * lane] * LOG2E;
  float a1 = a[DDIM + 2 * lane + 1] * LOG2E;
#pragma unroll
  for (int i = 0; i < 4; ++i) {
    int j = blk * 16 + w * 4 + i;
    float2 v = *(const float2*)(V + (long)j * DDIM + 2 * lane);
    float d = wave_reduce_add(v.x * a0 + v.y * a1);
    if (lane == 0) sneigh[j] = d;
  }

  const int tg = blk * 256 + t;       // == chunkid*64 + lane
  const int l = tg & 63;
  const int chunkid = tg >> 6;        // 0..1023
  const int c = chunkid & 15, kt = chunkid >> 4;
  const int ks2 = c >> 3, cf = c & 7;
  const int col = cf * 16 + (l & 15);
  const long krow = (long)kt * 64 + ks2 * 32 + (l >> 4) * 8;
  short8 o;
#pragma unroll
  for (int b = 0; b < 8; ++b) {
    float f = V[(krow + b) * DDIM + col];
    o[b] = (short)f2bf(f);
  }
  *(short8*)(packedV + (long)tg * 8) = o;
}

// ---------------------------------------------------------------------------
// K2: main. 256 blocks x 512 threads (8 waves = 4 row-waves x 2 K-split).
// Mask now comes from the bitmask (8 B/thread/iter, L1/L2-resident).
// ---------------------------------------------------------------------------
__global__ __launch_bounds__(512, 2) void aggr_main(
    const float* __restrict__ self_feats, const unsigned char* __restrict__ bm,
    const float* __restrict__ a, const float* __restrict__ sneigh,
    const short* __restrict__ packedV, float* __restrict__ out) {
  __shared__ float s_sn[MCOLS];                    // 16 KB: s_neigh'
  __shared__ float s_ss[64];                       // s_self' for block rows
  __shared__ __align__(16) short Bst[2][2][8192];  // 64 KB: [dbuf][ks][16KB tile]
  __shared__ float comb[4][16][132];               // 33 KB: ks=1 partial acc
  __shared__ float den_x[64];                      // ks=1 partial den
  __shared__ float den_f[64];                      // final den per row

  const int t = threadIdx.x, lane = t & 63, w = t >> 6;
  const int rw = w & 3, ks = w >> 2;
  const int blk = blockIdx.x;
  const int rowblk = blk * 64;
  const int arow = lane & 15, kg = lane >> 4;

  // s_self' : 8 rows per wave
  {
    float a0 = a[2 * lane] * LOG2E, a1 = a[2 * lane + 1] * LOG2E;
#pragma unroll
    for (int i = 0; i < 8; ++i) {
      int r = w * 8 + i;
      float2 v = *(const float2*)(self_feats + (long)(rowblk + r) * DDIM + 2 * lane);
      float d = wave_reduce_add(v.x * a0 + v.y * a1);
      if (lane == 0) s_ss[r] = d;
    }
  }
  // s_neigh' -> LDS (coalesced)
  {
    const float4* src = (const float4*)sneigh;
    float4* dst = (float4*)s_sn;
    dst[t] = src[t];
    dst[t + 512] = src[t + 512];
  }

  // stage one ks-half B tile (16 chunks of 1KB) into LDS; 4 chunks per wave
  auto STAGE = [&](int buf, int it2) {
    int ktn = it2 * 2 + ks;
#pragma unroll
    for (int j = 0; j < 4; ++j) {
      int c = (w & 3) * 4 + j;
      const short* g = packedV + ((long)(ktn * 16 + c) * 64 + lane) * 8;
      __builtin_amdgcn_global_load_lds(
          (const __attribute__((address_space(1))) void*)g,
          (__attribute__((address_space(3))) void*)(&Bst[buf][ks][c * 512]),
          16, 0, 0);
    }
  };

  const unsigned char* bmrow = bm + (long)(rowblk + rw * 16 + arow) * 512;

  u64 mu_c, mu_n = 0;
  STAGE(0, 0);
  mu_c = *(const u64*)(bmrow + ks * 8);
  __syncthreads();  // covers s_ss, s_sn and STAGE(0,0)

  const float si = s_ss[rw * 16 + arow];

  f32x4 acc[8];
#pragma unroll
  for (int i = 0; i < 8; ++i) acc[i] = (f32x4){0.f, 0.f, 0.f, 0.f};
  float den = 0.f;

  for (int it = 0; it < 32; ++it) {
    const int kt = it * 2 + ks;
    const int buf = it & 1;
    if (it < 31) {
      STAGE(buf ^ 1, it + 1);
      mu_n = *(const u64*)(bmrow + ((it + 1) * 2 + ks) * 8);
    }

    short8 afr[2];
#pragma unroll
    for (int ks2 = 0; ks2 < 2; ++ks2) {
      const float* sj = &s_sn[kt * 64 + ks2 * 32 + kg * 8];
      float4 s0 = *(const float4*)sj;
      float4 s1 = *(const float4*)(sj + 4);
      unsigned mb = (unsigned)(mu_c >> (ks2 * 32 + kg * 8)) & 0xffu;
      float p0 = pcalc(si + s0.x, (int)(mb & 1u));
      float p1 = pcalc(si + s0.y, (int)(mb & 2u));
      float p2 = pcalc(si + s0.z, (int)(mb & 4u));
      float p3 = pcalc(si + s0.w, (int)(mb & 8u));
      float p4 = pcalc(si + s1.x, (int)(mb & 16u));
      float p5 = pcalc(si + s1.y, (int)(mb & 32u));
      float p6 = pcalc(si + s1.z, (int)(mb & 64u));
      float p7 = pcalc(si + s1.w, (int)(mb & 128u));
      den += ((p0 + p1) + (p2 + p3)) + ((p4 + p5) + (p6 + p7));
      int4 ai;
      ai.x = (int)pack_bf2(p0, p1);
      ai.y = (int)pack_bf2(p2, p3);
      ai.z = (int)pack_bf2(p4, p5);
      ai.w = (int)pack_bf2(p6, p7);
      afr[ks2] = __builtin_bit_cast(short8, ai);
    }

    const short8* Bks = (const short8*)&Bst[buf][ks][0];
#pragma unroll
    for (int cf = 0; cf < 8; ++cf) {
      acc[cf] = __builtin_amdgcn_mfma_f32_16x16x32_bf16(afr[0], Bks[cf * 64 + lane], acc[cf], 0, 0, 0);
      acc[cf] = __builtin_amdgcn_mfma_f32_16x16x32_bf16(afr[1], Bks[(8 + cf) * 64 + lane], acc[cf], 0, 0, 0);
    }

    __syncthreads();  // drains stage + mask prefetch; protects dbuf swap
    mu_c = mu_n;
  }

  // den: sum the 4 k-groups -> every lane holds den(row = arow) for its ks half
  den += __shfl_xor(den, 16, 64);
  den += __shfl_xor(den, 32, 64);

  if (ks == 1) {
#pragma unroll
    for (int cf = 0; cf < 8; ++cf)
#pragma unroll
      for (int r = 0; r < 4; ++r)
        comb[rw][kg * 4 + r][cf * 16 + arow] = acc[cf][r];
    if (lane < 16) den_x[rw * 16 + lane] = den;
  }
  __syncthreads();
  if (ks == 0) {
    float dtot = den + den_x[rw * 16 + arow];
    if (lane < 16) den_f[rw * 16 + lane] = dtot;
  }
  __syncthreads();
  if (ks == 0) {
    float rcp[4];
#pragma unroll
    for (int r = 0; r < 4; ++r) {
      float dv = den_f[rw * 16 + kg * 4 + r];
      rcp[r] = dv > 0.f ? 1.0f / dv : 0.f;
    }
#pragma unroll
    for (int cf = 0; cf < 8; ++cf)
#pragma unroll
      for (int r = 0; r < 4; ++r) {
        float v = (acc[cf][r] + comb[rw][kg * 4 + r][cf * 16 + arow]) * rcp[r];
        out[(long)(rowblk + rw * 16 + kg * 4 + r) * DDIM + cf * 16 + arow] = v;
      }
  }
}

extern "C" void kernel_launch(void* const* d_in, const int* in_sizes, int n_in,
                              void* d_out, int out_size, void* d_ws, size_t ws_size,
                              hipStream_t stream) {
  const float* self_feats = (const float*)d_in[0];
  const float* V = (const float*)d_in[1];           // features_neighs
  const int* nm = (const int*)d_in[2];              // neigh_matrix
  const float* a = (const float*)d_in[3];
  float* out = (float*)d_out;

  float* sneigh = (float*)d_ws;                              // 16 KB @ 0
  short* packedV = (short*)((char*)d_ws + (1 << 14));        // 1 MB @ 16 KB
  u64* bm64 = (u64*)((char*)d_ws + (1 << 21));               // 8.4 MB @ 2 MB

  aggr_pack<<<4096, 256, 0, stream>>>((const int4*)nm, bm64);
  aggr_prep<<<256, 256, 0, stream>>>(V, a, sneigh, packedV);
  aggr_main<<<256, 512, 0, stream>>>(self_feats, (const unsigned char*)bm64,
                                     a, sneigh, packedV, out);
}

// Round 4
// 400.492 us; speedup vs baseline: 1.0530x; 1.0530x over previous
//
#include <hip/hip_runtime.h>
#include <hip/hip_bf16.h>

#define NROWS 16384
#define MCOLS 4096
#define DDIM  128
#define LOG2E 1.4426950408889634f

typedef __attribute__((ext_vector_type(8))) short short8;
typedef __attribute__((ext_vector_type(4))) float f32x4;

__device__ __forceinline__ float wave_reduce_add(float d) {
#pragma unroll
  for (int off = 32; off >= 1; off >>= 1) d += __shfl_xor(d, off, 64);
  return d;
}

__device__ __forceinline__ float pcalc(float t, int m) {
  float u = fmaxf(t, 0.2f * t);   // leaky_relu (commutes with positive log2e scaling)
  float e = exp2f(u);             // inputs pre-scaled by log2e
  return m != 0 ? e : 0.f;
}

// round-to-nearest-even f32 -> bf16 (valid for finite non-NaN inputs)
__device__ __forceinline__ unsigned short f2bf(float f) {
  unsigned u = __builtin_bit_cast(unsigned, f);
  return (unsigned short)((u + 0x7fffu + ((u >> 16) & 1u)) >> 16);
}

__device__ __forceinline__ unsigned pack_bf2(float lo, float hi) {
  return (unsigned)f2bf(lo) | ((unsigned)f2bf(hi) << 16);
}

// ---------------------------------------------------------------------------
// K1: s_neigh' = (V @ a_neigh)*log2e ; pack V -> bf16 in MFMA-B fragment order.
// chunkid = kt*16 + (ks2*8 + cf); entry = chunkid*64 + lane holds B[k][col]
// for k = kt*64 + ks2*32 + (lane>>4)*8 + b (b=0..7), col = cf*16 + (lane&15).
// ---------------------------------------------------------------------------
__global__ __launch_bounds__(256) void aggr_prep(
    const float* __restrict__ V, const float* __restrict__ a,
    float* __restrict__ sneigh, short* __restrict__ packedV) {
  const int t = threadIdx.x, lane = t & 63, w = t >> 6;
  const int blk = blockIdx.x;  // 0..255

  float a0 = a[DDIM + 2 * lane] * LOG2E;
  float a1 = a[DDIM + 2 * lane + 1] * LOG2E;
#pragma unroll
  for (int i = 0; i < 4; ++i) {
    int j = blk * 16 + w * 4 + i;
    float2 v = *(const float2*)(V + (long)j * DDIM + 2 * lane);
    float d = wave_reduce_add(v.x * a0 + v.y * a1);
    if (lane == 0) sneigh[j] = d;
  }

  const int tg = blk * 256 + t;       // == chunkid*64 + lane
  const int l = tg & 63;
  const int chunkid = tg >> 6;        // 0..1023
  const int c = chunkid & 15, kt = chunkid >> 4;
  const int ks2 = c >> 3, cf = c & 7;
  const int col = cf * 16 + (l & 15);
  const long krow = (long)kt * 64 + ks2 * 32 + (l >> 4) * 8;
  short8 o;
#pragma unroll
  for (int b = 0; b < 8; ++b) {
    float f = V[(krow + b) * DDIM + col];
    o[b] = (short)f2bf(f);
  }
  *(short8*)(packedV + (long)tg * 8) = o;
}

// ---------------------------------------------------------------------------
// K2: main. 256 blocks x 512 threads (8 waves = 4 row-waves x 2 K-split).
// Single pass over the 268 MB mask (the binding HBM stream). Per iter:
// [STAGE next B half-tile | fence | mask prefetch | fence] -> P compute +
// 16 MFMA -> s_waitcnt vmcnt(4) (STAGE retired, mask loads stay in flight
// ACROSS the barrier) -> raw s_barrier. No vmcnt(0) drain in the loop.
// ---------------------------------------------------------------------------
__global__ __launch_bounds__(512, 2) void aggr_main(
    const float* __restrict__ self_feats, const int* __restrict__ nm,
    const float* __restrict__ a, const float* __restrict__ sneigh,
    const short* __restrict__ packedV, float* __restrict__ out) {
  __shared__ float s_sn[MCOLS];                    // 16 KB: s_neigh'
  __shared__ float s_ss[64];                       // s_self' for block rows
  __shared__ __align__(16) short Bst[2][2][8192];  // 64 KB: [dbuf][ks][16KB tile]
  __shared__ float comb[4][16][132];               // 33 KB: ks=1 partial acc
  __shared__ float den_x[64];                      // ks=1 partial den
  __shared__ float den_f[64];                      // final den per row

  const int t = threadIdx.x, lane = t & 63, w = t >> 6;
  const int rw = w & 3, ks = w >> 2;
  const int blk = blockIdx.x;
  const int rowblk = blk * 64;
  const int arow = lane & 15, kg = lane >> 4;

  // s_self' : 8 rows per wave
  {
    float a0 = a[2 * lane] * LOG2E, a1 = a[2 * lane + 1] * LOG2E;
#pragma unroll
    for (int i = 0; i < 8; ++i) {
      int r = w * 8 + i;
      float2 v = *(const float2*)(self_feats + (long)(rowblk + r) * DDIM + 2 * lane);
      float d = wave_reduce_add(v.x * a0 + v.y * a1);
      if (lane == 0) s_ss[r] = d;
    }
  }
  // s_neigh' -> LDS (coalesced)
  {
    const float4* src = (const float4*)sneigh;
    float4* dst = (float4*)s_sn;
    dst[t] = src[t];
    dst[t + 512] = src[t + 512];
  }

  // stage one ks-half B tile (16 chunks of 1KB) into LDS; 4 chunks per wave
  auto STAGE = [&](int buf, int it2) {
    int ktn = it2 * 2 + ks;
#pragma unroll
    for (int j = 0; j < 4; ++j) {
      int c = (w & 3) * 4 + j;
      const short* g = packedV + ((long)(ktn * 16 + c) * 64 + lane) * 8;
      __builtin_amdgcn_global_load_lds(
          (const __attribute__((address_space(1))) void*)g,
          (__attribute__((address_space(3))) void*)(&Bst[buf][ks][c * 512]),
          16, 0, 0);
    }
  };

  const int* mbase = nm + (long)(rowblk + rw * 16 + arow) * MCOLS + kg * 8;

  int4 mc[4], mn[4] = {};
  STAGE(0, 0);
  {
    const int kt0 = ks;
#pragma unroll
    for (int ks2 = 0; ks2 < 2; ++ks2)
#pragma unroll
      for (int q = 0; q < 2; ++q)
        mc[ks2 * 2 + q] = *(const int4*)(mbase + kt0 * 64 + ks2 * 32 + q * 4);
  }
  __syncthreads();  // prologue: covers s_ss, s_sn writes and STAGE(0,0)

  const float si = s_ss[rw * 16 + arow];

  f32x4 acc[8];
#pragma unroll
  for (int i = 0; i < 8; ++i) acc[i] = (f32x4){0.f, 0.f, 0.f, 0.f};
  float den = 0.f;

#pragma unroll 2
  for (int it = 0; it < 32; ++it) {
    const int kt = it * 2 + ks;
    const int buf = it & 1;
    if (it < 31) {
      STAGE(buf ^ 1, it + 1);
      __builtin_amdgcn_sched_barrier(0);  // pin: STAGE issued before mask loads
      const int ktn = (it + 1) * 2 + ks;
#pragma unroll
      for (int ks2 = 0; ks2 < 2; ++ks2)
#pragma unroll
        for (int q = 0; q < 2; ++q)
          mn[ks2 * 2 + q] = *(const int4*)(mbase + ktn * 64 + ks2 * 32 + q * 4);
      __builtin_amdgcn_sched_barrier(0);  // pin: mask loads issued here, not later
    }

    short8 afr[2];
#pragma unroll
    for (int ks2 = 0; ks2 < 2; ++ks2) {
      const float* sj = &s_sn[kt * 64 + ks2 * 32 + kg * 8];
      float4 s0 = *(const float4*)sj;
      float4 s1 = *(const float4*)(sj + 4);
      int4 m0 = mc[ks2 * 2], m1 = mc[ks2 * 2 + 1];
      float p0 = pcalc(si + s0.x, m0.x);
      float p1 = pcalc(si + s0.y, m0.y);
      float p2 = pcalc(si + s0.z, m0.z);
      float p3 = pcalc(si + s0.w, m0.w);
      float p4 = pcalc(si + s1.x, m1.x);
      float p5 = pcalc(si + s1.y, m1.y);
      float p6 = pcalc(si + s1.z, m1.z);
      float p7 = pcalc(si + s1.w, m1.w);
      den += ((p0 + p1) + (p2 + p3)) + ((p4 + p5) + (p6 + p7));
      int4 ai;
      ai.x = (int)pack_bf2(p0, p1);
      ai.y = (int)pack_bf2(p2, p3);
      ai.z = (int)pack_bf2(p4, p5);
      ai.w = (int)pack_bf2(p6, p7);
      afr[ks2] = __builtin_bit_cast(short8, ai);
    }

    const short8* Bks = (const short8*)&Bst[buf][ks][0];
#pragma unroll
    for (int cf = 0; cf < 8; ++cf) {
      acc[cf] = __builtin_amdgcn_mfma_f32_16x16x32_bf16(afr[0], Bks[cf * 64 + lane], acc[cf], 0, 0, 0);
      acc[cf] = __builtin_amdgcn_mfma_f32_16x16x32_bf16(afr[1], Bks[(8 + cf) * 64 + lane], acc[cf], 0, 0, 0);
    }

    // Own STAGE (4 oldest of the 8 in flight) retired; the 4 mask loads stay
    // outstanding across the barrier. At it==31 nothing is in flight: no-op.
    asm volatile("s_waitcnt vmcnt(4)" ::: "memory");
    __builtin_amdgcn_sched_barrier(0);
    __builtin_amdgcn_s_barrier();
    mc[0] = mn[0]; mc[1] = mn[1]; mc[2] = mn[2]; mc[3] = mn[3];
  }

  // den: sum the 4 k-groups -> every lane holds den(row = arow) for its ks half
  den += __shfl_xor(den, 16, 64);
  den += __shfl_xor(den, 32, 64);

  if (ks == 1) {
#pragma unroll
    for (int cf = 0; cf < 8; ++cf)
#pragma unroll
      for (int r = 0; r < 4; ++r)
        comb[rw][kg * 4 + r][cf * 16 + arow] = acc[cf][r];
    if (lane < 16) den_x[rw * 16 + lane] = den;
  }
  __syncthreads();
  if (ks == 0) {
    float dtot = den + den_x[rw * 16 + arow];
    if (lane < 16) den_f[rw * 16 + lane] = dtot;
  }
  __syncthreads();
  if (ks == 0) {
    float rcp[4];
#pragma unroll
    for (int r = 0; r < 4; ++r) {
      float dv = den_f[rw * 16 + kg * 4 + r];
      rcp[r] = dv > 0.f ? 1.0f / dv : 0.f;
    }
#pragma unroll
    for (int cf = 0; cf < 8; ++cf)
#pragma unroll
      for (int r = 0; r < 4; ++r) {
        float v = (acc[cf][r] + comb[rw][kg * 4 + r][cf * 16 + arow]) * rcp[r];
        out[(long)(rowblk + rw * 16 + kg * 4 + r) * DDIM + cf * 16 + arow] = v;
      }
  }
}

extern "C" void kernel_launch(void* const* d_in, const int* in_sizes, int n_in,
                              void* d_out, int out_size, void* d_ws, size_t ws_size,
                              hipStream_t stream) {
  const float* self_feats = (const float*)d_in[0];
  const float* V = (const float*)d_in[1];           // features_neighs
  const int* nm = (const int*)d_in[2];              // neigh_matrix
  const float* a = (const float*)d_in[3];
  float* out = (float*)d_out;

  float* sneigh = (float*)d_ws;                     // 16 KB @ 0
  short* packedV = (short*)((char*)d_ws + 16384);   // 1 MB @ 16 KB

  aggr_prep<<<256, 256, 0, stream>>>(V, a, sneigh, packedV);
  aggr_main<<<256, 512, 0, stream>>>(self_feats, nm, a, sneigh, packedV, out);
}